// Round 20
// baseline (785.685 us; speedup 1.0000x reference)
//
#include <hip/hip_runtime.h>

#define NB 4
#define NH 1024
#define NW 1024
#define NHW (NH * NW)

#define TS 32          // owned output tile side
#define HP 16          // halo
#define SRCS 64        // source region side = TS + 2*HP
#define SRC_PX (SRCS * SRCS)   // 4096
#define TILE_PX (TS * TS)      // 1024

__device__ __forceinline__ float srgb2lin(float v) {
    return v > 0.04045f ? powf((v + 0.055f) * (1.0f / 1.055f), 2.4f) : v * (1.0f / 12.92f);
}

__device__ __forceinline__ float labf(float t) {
    return t > 0.008856f ? cbrtf(t) : 7.787f * t + 4.0f / 29.0f;
}

// Lab for both images, 4 px/thread with float4 plane loads (G13: vectorize
// streaming kernels). Output FLOAT4-padded (hw,4) for single-load gathers.
__global__ __launch_bounds__(256) void lab_kernel(
        const float* __restrict__ I0, const float* __restrict__ I1,
        float4* __restrict__ lab0, float4* __restrict__ lab1) {
    int idx = blockIdx.x * blockDim.x + threadIdx.x;   // group of 4 px
    const int total = 2 * NB * NHW / 4;
    if (idx >= total) return;
    int img = (idx >= NB * NHW / 4) ? 1 : 0;
    int p = idx - img * (NB * NHW / 4);
    int b = p / (NHW / 4);
    int hw = (p - b * (NHW / 4)) * 4;

    const float* src = (img ? I1 : I0) + (size_t)b * 3 * NHW + hw;
    float4* dst = (img ? lab1 : lab0) + ((size_t)b * NHW + hw);

    const float4 r4 = *(const float4*)(src);
    const float4 g4 = *(const float4*)(src + NHW);
    const float4 b4 = *(const float4*)(src + 2 * NHW);
    const float rv[4] = {r4.x, r4.y, r4.z, r4.w};
    const float gv[4] = {g4.x, g4.y, g4.z, g4.w};
    const float bv[4] = {b4.x, b4.y, b4.z, b4.w};

#pragma unroll
    for (int j = 0; j < 4; ++j) {
        float r = srgb2lin(rv[j]);
        float g = srgb2lin(gv[j]);
        float bl = srgb2lin(bv[j]);

        float X = (0.412453f * r + 0.35758f * g + 0.180423f * bl) * (1.0f / 0.95047f);
        float Y = (0.212671f * r + 0.71516f * g + 0.072169f * bl);
        float Z = (0.019334f * r + 0.119193f * g + 0.950227f * bl) * (1.0f / 1.08883f);

        float fx = labf(X);
        float fy = labf(Y);
        float fz = labf(Z);

        dst[j] = make_float4(116.0f * fy - 16.0f, 500.0f * (fx - fy),
                             200.0f * (fy - fz), 0.0f);
    }
}

// z-metric + exp + premultiply, both directions in one launch (z in [0,2*NB)).
// 4 px/thread: float4 loads on flow/img planes, float4 stores on pm; the 4
// lab4 bilinear corners remain per-px single 16B loads.
__global__ __launch_bounds__(256) void wmap_kernel(
        const float4* __restrict__ lab0, const float4* __restrict__ lab1,
        const float* __restrict__ I0, const float* __restrict__ I1,
        const float* __restrict__ f01, const float* __restrict__ f10,
        float4* __restrict__ pm0, float4* __restrict__ pm1) {
    const int z = blockIdx.z;
    const int dir = z >> 2;            // NB == 4
    const int b = z & (NB - 1);
    const int tx = (threadIdx.x & 31) * 4;
    const int ty = threadIdx.x >> 5;
    const int x = blockIdx.x * 128 + tx;
    const int y = blockIdx.y * 8 + ty;
    const int hw = y * NW + x;

    const float4* la  = (dir ? lab1 : lab0) + (size_t)b * NHW;
    const float4* lb  = (dir ? lab0 : lab1) + (size_t)b * NHW;
    const float* img = (dir ? I1 : I0) + (size_t)b * 3 * NHW;
    const float* fb  = (dir ? f10 : f01) + (size_t)b * 2 * NHW;
    float4* pm = (dir ? pm1 : pm0) + (size_t)b * NHW;

    const float4 fy4 = *(const float4*)(fb + hw);
    const float4 fx4 = *(const float4*)(fb + NHW + hw);
    const float4 i04 = *(const float4*)(img + hw);
    const float4 i14 = *(const float4*)(img + NHW + hw);
    const float4 i24 = *(const float4*)(img + 2 * NHW + hw);
    const float fyv[4] = {fy4.x, fy4.y, fy4.z, fy4.w};
    const float fxv[4] = {fx4.x, fx4.y, fx4.z, fx4.w};
    const float i0v[4] = {i04.x, i04.y, i04.z, i04.w};
    const float i1v[4] = {i14.x, i14.y, i14.z, i14.w};
    const float i2v[4] = {i24.x, i24.y, i24.z, i24.w};

#pragma unroll
    for (int j = 0; j < 4; ++j) {
        const int xj = x + j;
        const float fy_d = fyv[j];
        const float fx_d = fxv[j];

        float base_y = -1.0f + 2.0f * (float)y / (float)(NH - 1);
        float base_x = -1.0f + 2.0f * (float)xj / (float)(NW - 1);
        float gy = 2.0f * fy_d / (float)NH + base_y;
        float gx = 2.0f * fx_d / (float)NW + base_x;
        float ys = fminf(fmaxf(((gy + 1.0f) * (float)NH - 1.0f) * 0.5f, 0.0f), (float)(NH - 1));
        float xs = fminf(fmaxf(((gx + 1.0f) * (float)NW - 1.0f) * 0.5f, 0.0f), (float)(NW - 1));
        float y0f = floorf(ys), x0f = floorf(xs);
        int y0 = (int)y0f, x0 = (int)x0f;
        int y1 = min(y0 + 1, NH - 1), x1 = min(x0 + 1, NW - 1);
        float wy = ys - y0f, wx = xs - x0f;

        const float4 p00 = lb[y0 * NW + x0];
        const float4 p01 = lb[y0 * NW + x1];
        const float4 p10 = lb[y1 * NW + x0];
        const float4 p11 = lb[y1 * NW + x1];
        const float4 pa  = la[hw + j];

        float vx = (p00.x * (1.0f - wx) + p01.x * wx) * (1.0f - wy)
                 + (p10.x * (1.0f - wx) + p11.x * wx) * wy;
        float vy = (p00.y * (1.0f - wx) + p01.y * wx) * (1.0f - wy)
                 + (p10.y * (1.0f - wx) + p11.y * wx) * wy;
        float vz = (p00.z * (1.0f - wx) + p01.z * wx) * (1.0f - wy)
                 + (p10.z * (1.0f - wx) + p11.z * wx) * wy;
        float dx_ = pa.x - vx, dy_ = pa.y - vy, dz_ = pa.z - vz;
        float ss = dx_ * dx_ + dy_ * dy_ + dz_ * dz_;
        float w = expf(-0.1f * sqrtf(ss));

        pm[hw + j] = make_float4(i0v[j] * w, i1v[j] * w, i2v[j] * w, w);
    }
}

// BIN + GATHER splat (r14/r16 structure — measured best at 251us).
// Flush: ONE plain coalesced float4 store per own px into acc4.
// Spills (interior-owned, uncovered, pre-tested max|flow|>15): float4-cell
// atomics into ovf (= d_out, zeroed).
__global__ __launch_bounds__(1024, 2) void splat_bin_kernel(
        const float4* __restrict__ pm0, const float4* __restrict__ pm1,
        const float* __restrict__ f01, const float* __restrict__ f10,
        float4* __restrict__ acc4,    // [2*NB*NHW) float4, dir-major
        float4* __restrict__ ovf) {   // [2*NB*NHW) float4, dir-major (zeroed)
    __shared__ unsigned       head[33 * 33];   // sentinel 0xFFFF
    __shared__ unsigned short nxt[SRC_PX];
    __shared__ float2         flows[SRC_PX];

    const int t = threadIdx.x;
    const int z = blockIdx.z;
    const int dir = z >> 2;
    const int b = z & (NB - 1);
    const int tx0 = blockIdx.x * TS;
    const int ty0 = blockIdx.y * TS;
    const int ox = tx0 - HP;
    const int oy = ty0 - HP;

    for (int i = t; i < 33 * 33; i += 1024) head[i] = 0xFFFFu;
    __syncthreads();

    const float4* pm = (dir ? pm1 : pm0) + (size_t)b * NHW;
    const float* fb  = (dir ? f10 : f01) + (size_t)b * 2 * NHW;
    float4* a4 = acc4 + ((size_t)dir * NB + b) * NHW;
    float4* ov = ovf  + ((size_t)dir * NB + b) * NHW;

    // ---- phase 1: bin sources by floor(target) cell ----
#pragma unroll
    for (int kk = 0; kk < 4; ++kk) {
        const int i = t + kk * 1024;   // SRC_PX == 4 * 1024
        const int rx = i & (SRCS - 1);
        const int ry = i >> 6;
        const int sx = ox + rx;
        const int sy = oy + ry;
        if (sx < 0 || sx >= NW || sy < 0 || sy >= NH) continue;
        const int hw = sy * NW + sx;

        const float fy_d = fb[hw];
        const float fx_d = fb[NHW + hw];
        flows[i] = make_float2(fx_d, fy_d);

        const float px = fx_d + (float)sx;
        const float py = fy_d + (float)sy;
        const int fcx = (int)floorf(px);
        const int fcy = (int)floorf(py);
        const int mx = fcx - tx0;      // margin-relative floor cell
        const int my = fcy - ty0;

        if (mx >= -1 && mx < TS && my >= -1 && my < TS) {
            unsigned old = atomicExch(&head[(my + 1) * 33 + (mx + 1)], (unsigned)i);
            nxt[i] = (unsigned short)old;
        }

        // interior-owned, uncovered taps -> ovf. Pre-test skips provably
        // covered sources (max|flow| <= 15).
        const bool interior = (rx >= HP) && (rx < HP + TS) && (ry >= HP) && (ry < HP + TS);
        if (interior && fmaxf(fabsf(fx_d), fabsf(fy_d)) > 15.0f) {
            float4 p4; bool loaded = false;
#pragma unroll
            for (int dy = 0; dy < 2; ++dy) {
                const int yi = fcy + dy;
                if (yi < 0 || yi >= NH) continue;
                const float wgy = 1.0f - fabsf(py - (float)yi);
#pragma unroll
                for (int dx = 0; dx < 2; ++dx) {
                    const int xi = fcx + dx;
                    if (xi < 0 || xi >= NW) continue;
                    const int ttx0 = xi & ~(TS - 1);
                    const int tty0 = yi & ~(TS - 1);
                    const bool covered = (sx >= ttx0 - HP) && (sx < ttx0 + TS + HP) &&
                                         (sy >= tty0 - HP) && (sy < tty0 + TS + HP);
                    if (!covered) {
                        if (!loaded) { p4 = pm[hw]; loaded = true; }
                        const float wg = wgy * (1.0f - fabsf(px - (float)xi));
                        float* p = (float*)(ov + (yi * NW + xi));
                        atomicAdd(p + 0, p4.x * wg);
                        atomicAdd(p + 1, p4.y * wg);
                        atomicAdd(p + 2, p4.z * wg);
                        atomicAdd(p + 3, p4.w * wg);
                    }
                }
            }
        }
    }
    __syncthreads();

    // ---- phase 2: gather own cell from the 4 relevant lists ----
    {
        const int lx = t & (TS - 1);
        const int ly = t >> 5;
        const int cx = tx0 + lx;
        const int cy = ty0 + ly;
        const float cxf = (float)cx;
        const float cyf = (float)cy;

        float sx_ = 0.0f, sy_ = 0.0f, sz_ = 0.0f, sw_ = 0.0f;

#pragma unroll
        for (int dy = 0; dy < 2; ++dy) {
#pragma unroll
            for (int dx = 0; dx < 2; ++dx) {
                unsigned e = head[(ly + 1 - dy) * 33 + (lx + 1 - dx)];
                int guard = SRC_PX;
                while (e != 0xFFFFu && --guard >= 0) {
                    const float2 f = flows[e];
                    const int rx = e & (SRCS - 1);
                    const int ry = (int)e >> 6;
                    const int sxx = ox + rx;
                    const int syy = oy + ry;
                    const float px = f.x + (float)sxx;
                    const float py = f.y + (float)syy;
                    const float wg = (1.0f - fabsf(px - cxf)) * (1.0f - fabsf(py - cyf));
                    const float4 p4 = pm[syy * NW + sxx];
                    sx_ += p4.x * wg;
                    sy_ += p4.y * wg;
                    sz_ += p4.z * wg;
                    sw_ += p4.w * wg;
                    e = nxt[e];
                }
            }
        }
        a4[cy * NW + cx] = make_float4(sx_, sy_, sz_, sw_);
    }
}

// Merge overflow into acc4 and emit a PLANAR w plane for morph staging.
__global__ __launch_bounds__(256) void merge_kernel(
        float4* __restrict__ acc4, const float4* __restrict__ ovf,
        float* __restrict__ wpl) {
    const size_t total = (size_t)2 * NB * NHW;
    for (size_t i = (size_t)blockIdx.x * blockDim.x + threadIdx.x; i < total;
         i += (size_t)gridDim.x * blockDim.x) {
        float4 a = acc4[i];
        float4 o = ovf[i];
        a.x += o.x; a.y += o.y; a.z += o.z; a.w += o.w;
        acc4[i] = a;
        wpl[i] = a.w;
    }
}

// Fused morph (separable erode+dilate) + blend + store. Staging +
// denominators from planar wpl; colors from merged acc4; write-only out.
// Staged path covers p<=8 (k<=17); brute-force beyond.
__global__ __launch_bounds__(256) void morph_compose_kernel(
        const float4* __restrict__ acc4, const float* __restrict__ wpl,
        float* __restrict__ out, const int* __restrict__ kptr) {
    __shared__ float bufOA[64 * 64], bufOB[64 * 64];   // occ (OS*OS) -> er (ES*ES)
    __shared__ float bufHA[64 * 48], bufHB[64 * 48];   // hmin (OS*ES) -> hmax (ES*32)

    const int t = threadIdx.x;
    const int b = blockIdx.z;
    const int x0 = blockIdx.x * 32;
    const int y0 = blockIdx.y * 32;
    const int k = *kptr;
    const int p = k >> 1;

    const float* wa = wpl + (size_t)b * NHW;                    // dir 0
    const float* wb = wpl + ((size_t)NB + b) * NHW;             // dir 1

    float mA[4], mB[4];

    if (p <= 8) {
        const int OS = 32 + 4 * p;
        const int ES = 32 + 2 * p;
        const int KW = 2 * p + 1;
        // stage occupancy (+inf pad: OOB = 1)
        for (int i = t; i < OS * OS; i += 256) {
            int sx = x0 - 2 * p + (i % OS);
            int sy = y0 - 2 * p + (i / OS);
            float oa = 1.0f, ob = 1.0f;
            if (sx >= 0 && sx < NW && sy >= 0 && sy < NH) {
                int o = sy * NW + sx;
                oa = (wa[o] != 0.0f) ? 1.0f : 0.0f;
                ob = (wb[o] != 0.0f) ? 1.0f : 0.0f;
            }
            bufOA[i] = oa; bufOB[i] = ob;
        }
        __syncthreads();
        // horizontal min: OS rows x ES cols
        for (int i = t; i < OS * ES; i += 256) {
            int y = i / ES, x = i % ES;
            float ma = 1.0f, mb = 1.0f;
            for (int d = 0; d < KW; ++d) {
                ma = fminf(ma, bufOA[y * OS + x + d]);
                mb = fminf(mb, bufOB[y * OS + x + d]);
            }
            bufHA[i] = ma; bufHB[i] = mb;
        }
        __syncthreads();
        // vertical min -> erode result (0 outside image: dilate -inf pad)
        for (int i = t; i < ES * ES; i += 256) {
            int ly = i / ES, lx = i % ES;
            int ex = x0 - p + lx, ey = y0 - p + ly;
            float ea = 0.0f, eb = 0.0f;
            if (ex >= 0 && ex < NW && ey >= 0 && ey < NH) {
                ea = 1.0f; eb = 1.0f;
                for (int d = 0; d < KW; ++d) {
                    ea = fminf(ea, bufHA[(ly + d) * ES + lx]);
                    eb = fminf(eb, bufHB[(ly + d) * ES + lx]);
                }
            }
            bufOA[i] = ea; bufOB[i] = eb;   // bufO reused for er
        }
        __syncthreads();
        // horizontal max: ES rows x 32 cols
        for (int i = t; i < ES * 32; i += 256) {
            int y = i >> 5, x = i & 31;
            float ma = 0.0f, mb = 0.0f;
            for (int d = 0; d < KW; ++d) {
                ma = fmaxf(ma, bufOA[y * ES + x + d]);
                mb = fmaxf(mb, bufOB[y * ES + x + d]);
            }
            bufHA[i] = ma; bufHB[i] = mb;   // bufH reused for hmax
        }
        __syncthreads();
        // vertical max -> dilate result for own 4 px
#pragma unroll
        for (int r = 0; r < 4; ++r) {
            int lx = t & 31, ly = (t >> 5) + r * 8;
            float ma = 0.0f, mb = 0.0f;
            for (int d = 0; d < KW; ++d) {
                ma = fmaxf(ma, bufHA[((ly + d) << 5) + lx]);
                mb = fmaxf(mb, bufHB[((ly + d) << 5) + lx]);
            }
            mA[r] = ma; mB[r] = mb;
        }
    } else {
        // brute-force fallback, never taken for k<=17; correctness insurance
#pragma unroll
        for (int r = 0; r < 4; ++r) {
            int x = x0 + (t & 31), y = y0 + (t >> 5) + r * 8;
            float ma = 0.0f, mb = 0.0f;
            for (int dy2 = -p; dy2 <= p; ++dy2) {
                int qy = y + dy2; if (qy < 0 || qy >= NH) continue;
                for (int dx2 = -p; dx2 <= p; ++dx2) {
                    int qx = x + dx2; if (qx < 0 || qx >= NW) continue;
                    if (ma >= 1.0f && mb >= 1.0f) break;
                    float ea = 1.0f, eb = 1.0f;
                    for (int dy = -p; dy <= p; ++dy) {
                        int yy = qy + dy; if (yy < 0 || yy >= NH) continue;
                        for (int dx = -p; dx <= p; ++dx) {
                            int xx = qx + dx; if (xx < 0 || xx >= NW) continue;
                            int o = yy * NW + xx;
                            if (wa[o] == 0.0f) ea = 0.0f;
                            if (wb[o] == 0.0f) eb = 0.0f;
                        }
                    }
                    ma = fmaxf(ma, ea);
                    mb = fmaxf(mb, eb);
                }
            }
            mA[r] = ma; mB[r] = mb;
        }
    }

    const float4* a0 = acc4 + (size_t)b * NHW;
    const float4* a1 = acc4 + ((size_t)NB + b) * NHW;
    float* o0 = out + (size_t)b * 4 * NHW;
    float* o1 = out + (size_t)NB * 4 * NHW + (size_t)b * 4 * NHW;

#pragma unroll
    for (int r = 0; r < 4; ++r) {
        int lx = t & 31, ly = (t >> 5) + r * 8;
        int x = x0 + lx, y = y0 + ly;
        int hw = y * NW + x;
        float4 v0 = a0[hw];
        float4 v1 = a1[hw];
        float d0 = (v0.w == 0.0f) ? 1.0f : v0.w;
        float d1 = (v1.w == 0.0f) ? 1.0f : v1.w;
        float m0 = mA[r], m1 = mB[r];
        float w00 = v0.x / d0, w01 = v0.y / d0, w02 = v0.z / d0;
        float w10 = v1.x / d1, w11 = v1.y / d1, w12 = v1.z / d1;
        o0[hw]           = m0 * w00 + (1.0f - m0) * w10;
        o0[NHW + hw]     = m0 * w01 + (1.0f - m0) * w11;
        o0[2 * NHW + hw] = m0 * w02 + (1.0f - m0) * w12;
        o0[3 * NHW + hw] = m0;
        o1[hw]           = m1 * w10 + (1.0f - m1) * w00;
        o1[NHW + hw]     = m1 * w11 + (1.0f - m1) * w01;
        o1[2 * NHW + hw] = m1 * w12 + (1.0f - m1) * w02;
        o1[3 * NHW + hw] = m1;
    }
}

extern "C" void kernel_launch(void* const* d_in, const int* in_sizes, int n_in,
                              void* d_out, int out_size, void* d_ws, size_t ws_size,
                              hipStream_t stream) {
    const float* I0  = (const float*)d_in[0];
    const float* I1  = (const float*)d_in[1];
    const float* f01 = (const float*)d_in[2];
    const float* f10 = (const float*)d_in[3];
    const int*  kptr = (const int*)d_in[4];

    float* ws = (float*)d_ws;
    const size_t n = (size_t)NB * NHW;
    // ws layout, 16n floats (proven footprint):
    //   [0, 8n)   pm0|pm1 (float4) during wmap+splat; wpl (2n floats)
    //             after splat (overlays dead pm).
    //   [8n, 16n) lab4 during lab/wmap; acc4 (2n float4) after (fully
    //             written by gather flush stores — no memset needed).
    // d_out doubles as the zeroed spill (ovf) buffer during splat; merge
    // folds it into acc4 before morph overwrites d_out.
    float4* pm0   = (float4*)ws;               // [0, 4n)
    float4* pm1   = (float4*)(ws + 4 * n);     // [4n, 8n)
    float*  wpl   = ws;                        // [0, 2n)  after splat
    float4* lab40 = (float4*)(ws + 8 * n);     // [8n, 12n)
    float4* lab41 = (float4*)(ws + 12 * n);    // [12n, 16n)
    float4* acc4  = (float4*)(ws + 8 * n);     // [8n, 16n) overlays lab4
    float4* ovf   = (float4*)d_out;            // spill scratch (zeroed)

    const int T = 256;
    int gLab = (2 * NB * NHW / 4 + T - 1) / T;
    dim3 gW(NW / 128, NH / 8, 2 * NB);
    dim3 gTile(NW / TS, NH / TS, 2 * NB);
    dim3 gCmp(NW / 32, NH / 32, NB);

    hipMemsetAsync(ovf, 0, 8 * n * sizeof(float), stream);   // zero spills
    lab_kernel<<<gLab, T, 0, stream>>>(I0, I1, lab40, lab41);
    wmap_kernel<<<gW, T, 0, stream>>>(lab40, lab41, I0, I1, f01, f10, pm0, pm1);
    splat_bin_kernel<<<gTile, 1024, 0, stream>>>(pm0, pm1, f01, f10, acc4, ovf);
    merge_kernel<<<4096, T, 0, stream>>>(acc4, ovf, wpl);
    morph_compose_kernel<<<gCmp, T, 0, stream>>>(acc4, wpl, (float*)d_out, kptr);
}

// Round 21
// 762.009 us; speedup vs baseline: 1.0311x; 1.0311x over previous
//
#include <hip/hip_runtime.h>

#define NB 4
#define NH 1024
#define NW 1024
#define NHW (NH * NW)

#define TS 32          // owned output tile side
#define HP 16          // halo
#define SRCS 64        // source region side = TS + 2*HP
#define SRC_PX (SRCS * SRCS)   // 4096
#define TILE_PX (TS * TS)      // 1024

__device__ __forceinline__ float srgb2lin(float v) {
    return v > 0.04045f ? powf((v + 0.055f) * (1.0f / 1.055f), 2.4f) : v * (1.0f / 12.92f);
}

__device__ __forceinline__ float labf(float t) {
    return t > 0.008856f ? cbrtf(t) : 7.787f * t + 4.0f / 29.0f;
}

// Lab for both images, 4 px/thread float4 plane loads (streaming-only, no
// gathers -> vectorization safe). Output FLOAT4-padded (hw,4).
__global__ __launch_bounds__(256) void lab_kernel(
        const float* __restrict__ I0, const float* __restrict__ I1,
        float4* __restrict__ lab0, float4* __restrict__ lab1) {
    int idx = blockIdx.x * blockDim.x + threadIdx.x;   // group of 4 px
    const int total = 2 * NB * NHW / 4;
    if (idx >= total) return;
    int img = (idx >= NB * NHW / 4) ? 1 : 0;
    int p = idx - img * (NB * NHW / 4);
    int b = p / (NHW / 4);
    int hw = (p - b * (NHW / 4)) * 4;

    const float* src = (img ? I1 : I0) + (size_t)b * 3 * NHW + hw;
    float4* dst = (img ? lab1 : lab0) + ((size_t)b * NHW + hw);

    const float4 r4 = *(const float4*)(src);
    const float4 g4 = *(const float4*)(src + NHW);
    const float4 b4 = *(const float4*)(src + 2 * NHW);
    const float rv[4] = {r4.x, r4.y, r4.z, r4.w};
    const float gv[4] = {g4.x, g4.y, g4.z, g4.w};
    const float bv[4] = {b4.x, b4.y, b4.z, b4.w};

#pragma unroll
    for (int j = 0; j < 4; ++j) {
        float r = srgb2lin(rv[j]);
        float g = srgb2lin(gv[j]);
        float bl = srgb2lin(bv[j]);

        float X = (0.412453f * r + 0.35758f * g + 0.180423f * bl) * (1.0f / 0.95047f);
        float Y = (0.212671f * r + 0.71516f * g + 0.072169f * bl);
        float Z = (0.019334f * r + 0.119193f * g + 0.950227f * bl) * (1.0f / 1.08883f);

        float fx = labf(X);
        float fy = labf(Y);
        float fz = labf(Z);

        dst[j] = make_float4(116.0f * fy - 16.0f, 500.0f * (fx - fy),
                             200.0f * (fy - fz), 0.0f);
    }
}

// z-metric + exp + premultiply, both directions in one launch (z in [0,2*NB)).
// SCALAR 1 px/thread (r17 measured config): wmap is latency-bound on the 4
// scattered lab4 gathers — max thread count is the latency-hiding resource
// (r20's 4px/thread variant cost ~+50us).
__global__ __launch_bounds__(256) void wmap_kernel(
        const float4* __restrict__ lab0, const float4* __restrict__ lab1,
        const float* __restrict__ I0, const float* __restrict__ I1,
        const float* __restrict__ f01, const float* __restrict__ f10,
        float4* __restrict__ pm0, float4* __restrict__ pm1) {
    const int z = blockIdx.z;
    const int dir = z >> 2;            // NB == 4
    const int b = z & (NB - 1);
    const int tx = threadIdx.x & 31;
    const int ty = threadIdx.x >> 5;
    const int x = blockIdx.x * 32 + tx;
    const int y = blockIdx.y * 8 + ty;
    const int hw = y * NW + x;

    const float4* la  = (dir ? lab1 : lab0) + (size_t)b * NHW;
    const float4* lb  = (dir ? lab0 : lab1) + (size_t)b * NHW;
    const float* img = (dir ? I1 : I0) + (size_t)b * 3 * NHW;
    const float* fb  = (dir ? f10 : f01) + (size_t)b * 2 * NHW;
    float4* pm = (dir ? pm1 : pm0) + (size_t)b * NHW;

    const float fy_d = fb[hw];
    const float fx_d = fb[NHW + hw];

    float base_y = -1.0f + 2.0f * (float)y / (float)(NH - 1);
    float base_x = -1.0f + 2.0f * (float)x / (float)(NW - 1);
    float gy = 2.0f * fy_d / (float)NH + base_y;
    float gx = 2.0f * fx_d / (float)NW + base_x;
    float ys = fminf(fmaxf(((gy + 1.0f) * (float)NH - 1.0f) * 0.5f, 0.0f), (float)(NH - 1));
    float xs = fminf(fmaxf(((gx + 1.0f) * (float)NW - 1.0f) * 0.5f, 0.0f), (float)(NW - 1));
    float y0f = floorf(ys), x0f = floorf(xs);
    int y0 = (int)y0f, x0 = (int)x0f;
    int y1 = min(y0 + 1, NH - 1), x1 = min(x0 + 1, NW - 1);
    float wy = ys - y0f, wx = xs - x0f;

    const float4 p00 = lb[y0 * NW + x0];
    const float4 p01 = lb[y0 * NW + x1];
    const float4 p10 = lb[y1 * NW + x0];
    const float4 p11 = lb[y1 * NW + x1];
    const float4 pa  = la[hw];

    float vx = (p00.x * (1.0f - wx) + p01.x * wx) * (1.0f - wy)
             + (p10.x * (1.0f - wx) + p11.x * wx) * wy;
    float vy = (p00.y * (1.0f - wx) + p01.y * wx) * (1.0f - wy)
             + (p10.y * (1.0f - wx) + p11.y * wx) * wy;
    float vz = (p00.z * (1.0f - wx) + p01.z * wx) * (1.0f - wy)
             + (p10.z * (1.0f - wx) + p11.z * wx) * wy;
    float dx_ = pa.x - vx, dy_ = pa.y - vy, dz_ = pa.z - vz;
    float ss = dx_ * dx_ + dy_ * dy_ + dz_ * dz_;
    float w = expf(-0.1f * sqrtf(ss));

    pm[hw] = make_float4(img[hw] * w, img[NHW + hw] * w, img[2 * NHW + hw] * w, w);
}

// BIN + GATHER splat (measured best: 251us). Flush: ONE plain coalesced
// float4 store per own px into acc4. Spills (interior-owned, uncovered,
// pre-tested max|flow|>15): float4-cell atomics into ovf (= d_out, zeroed).
__global__ __launch_bounds__(1024, 2) void splat_bin_kernel(
        const float4* __restrict__ pm0, const float4* __restrict__ pm1,
        const float* __restrict__ f01, const float* __restrict__ f10,
        float4* __restrict__ acc4,    // [2*NB*NHW) float4, dir-major
        float4* __restrict__ ovf) {   // [2*NB*NHW) float4, dir-major (zeroed)
    __shared__ unsigned       head[33 * 33];   // sentinel 0xFFFF
    __shared__ unsigned short nxt[SRC_PX];
    __shared__ float2         flows[SRC_PX];

    const int t = threadIdx.x;
    const int z = blockIdx.z;
    const int dir = z >> 2;
    const int b = z & (NB - 1);
    const int tx0 = blockIdx.x * TS;
    const int ty0 = blockIdx.y * TS;
    const int ox = tx0 - HP;
    const int oy = ty0 - HP;

    for (int i = t; i < 33 * 33; i += 1024) head[i] = 0xFFFFu;
    __syncthreads();

    const float4* pm = (dir ? pm1 : pm0) + (size_t)b * NHW;
    const float* fb  = (dir ? f10 : f01) + (size_t)b * 2 * NHW;
    float4* a4 = acc4 + ((size_t)dir * NB + b) * NHW;
    float4* ov = ovf  + ((size_t)dir * NB + b) * NHW;

    // ---- phase 1: bin sources by floor(target) cell ----
#pragma unroll
    for (int kk = 0; kk < 4; ++kk) {
        const int i = t + kk * 1024;   // SRC_PX == 4 * 1024
        const int rx = i & (SRCS - 1);
        const int ry = i >> 6;
        const int sx = ox + rx;
        const int sy = oy + ry;
        if (sx < 0 || sx >= NW || sy < 0 || sy >= NH) continue;
        const int hw = sy * NW + sx;

        const float fy_d = fb[hw];
        const float fx_d = fb[NHW + hw];
        flows[i] = make_float2(fx_d, fy_d);

        const float px = fx_d + (float)sx;
        const float py = fy_d + (float)sy;
        const int fcx = (int)floorf(px);
        const int fcy = (int)floorf(py);
        const int mx = fcx - tx0;      // margin-relative floor cell
        const int my = fcy - ty0;

        if (mx >= -1 && mx < TS && my >= -1 && my < TS) {
            unsigned old = atomicExch(&head[(my + 1) * 33 + (mx + 1)], (unsigned)i);
            nxt[i] = (unsigned short)old;
        }

        // interior-owned, uncovered taps -> ovf. Pre-test skips provably
        // covered sources (max|flow| <= 15).
        const bool interior = (rx >= HP) && (rx < HP + TS) && (ry >= HP) && (ry < HP + TS);
        if (interior && fmaxf(fabsf(fx_d), fabsf(fy_d)) > 15.0f) {
            float4 p4; bool loaded = false;
#pragma unroll
            for (int dy = 0; dy < 2; ++dy) {
                const int yi = fcy + dy;
                if (yi < 0 || yi >= NH) continue;
                const float wgy = 1.0f - fabsf(py - (float)yi);
#pragma unroll
                for (int dx = 0; dx < 2; ++dx) {
                    const int xi = fcx + dx;
                    if (xi < 0 || xi >= NW) continue;
                    const int ttx0 = xi & ~(TS - 1);
                    const int tty0 = yi & ~(TS - 1);
                    const bool covered = (sx >= ttx0 - HP) && (sx < ttx0 + TS + HP) &&
                                         (sy >= tty0 - HP) && (sy < tty0 + TS + HP);
                    if (!covered) {
                        if (!loaded) { p4 = pm[hw]; loaded = true; }
                        const float wg = wgy * (1.0f - fabsf(px - (float)xi));
                        float* p = (float*)(ov + (yi * NW + xi));
                        atomicAdd(p + 0, p4.x * wg);
                        atomicAdd(p + 1, p4.y * wg);
                        atomicAdd(p + 2, p4.z * wg);
                        atomicAdd(p + 3, p4.w * wg);
                    }
                }
            }
        }
    }
    __syncthreads();

    // ---- phase 2: gather own cell from the 4 relevant lists ----
    {
        const int lx = t & (TS - 1);
        const int ly = t >> 5;
        const int cx = tx0 + lx;
        const int cy = ty0 + ly;
        const float cxf = (float)cx;
        const float cyf = (float)cy;

        float sx_ = 0.0f, sy_ = 0.0f, sz_ = 0.0f, sw_ = 0.0f;

#pragma unroll
        for (int dy = 0; dy < 2; ++dy) {
#pragma unroll
            for (int dx = 0; dx < 2; ++dx) {
                unsigned e = head[(ly + 1 - dy) * 33 + (lx + 1 - dx)];
                int guard = SRC_PX;
                while (e != 0xFFFFu && --guard >= 0) {
                    const float2 f = flows[e];
                    const int rx = e & (SRCS - 1);
                    const int ry = (int)e >> 6;
                    const int sxx = ox + rx;
                    const int syy = oy + ry;
                    const float px = f.x + (float)sxx;
                    const float py = f.y + (float)syy;
                    const float wg = (1.0f - fabsf(px - cxf)) * (1.0f - fabsf(py - cyf));
                    const float4 p4 = pm[syy * NW + sxx];
                    sx_ += p4.x * wg;
                    sy_ += p4.y * wg;
                    sz_ += p4.z * wg;
                    sw_ += p4.w * wg;
                    e = nxt[e];
                }
            }
        }
        a4[cy * NW + cx] = make_float4(sx_, sy_, sz_, sw_);
    }
}

// Merge overflow into acc4 and emit a PLANAR w plane for morph staging.
__global__ __launch_bounds__(256) void merge_kernel(
        float4* __restrict__ acc4, const float4* __restrict__ ovf,
        float* __restrict__ wpl) {
    const size_t total = (size_t)2 * NB * NHW;
    for (size_t i = (size_t)blockIdx.x * blockDim.x + threadIdx.x; i < total;
         i += (size_t)gridDim.x * blockDim.x) {
        float4 a = acc4[i];
        float4 o = ovf[i];
        a.x += o.x; a.y += o.y; a.z += o.z; a.w += o.w;
        acc4[i] = a;
        wpl[i] = a.w;
    }
}

// Fused morph (separable erode+dilate) + blend + store. Staging +
// denominators from planar wpl; colors from merged acc4; write-only out.
// Staged path covers p<=8 (k<=17); brute-force beyond.
__global__ __launch_bounds__(256) void morph_compose_kernel(
        const float4* __restrict__ acc4, const float* __restrict__ wpl,
        float* __restrict__ out, const int* __restrict__ kptr) {
    __shared__ float bufOA[64 * 64], bufOB[64 * 64];   // occ (OS*OS) -> er (ES*ES)
    __shared__ float bufHA[64 * 48], bufHB[64 * 48];   // hmin (OS*ES) -> hmax (ES*32)

    const int t = threadIdx.x;
    const int b = blockIdx.z;
    const int x0 = blockIdx.x * 32;
    const int y0 = blockIdx.y * 32;
    const int k = *kptr;
    const int p = k >> 1;

    const float* wa = wpl + (size_t)b * NHW;                    // dir 0
    const float* wb = wpl + ((size_t)NB + b) * NHW;             // dir 1

    float mA[4], mB[4];

    if (p <= 8) {
        const int OS = 32 + 4 * p;
        const int ES = 32 + 2 * p;
        const int KW = 2 * p + 1;
        // stage occupancy (+inf pad: OOB = 1)
        for (int i = t; i < OS * OS; i += 256) {
            int sx = x0 - 2 * p + (i % OS);
            int sy = y0 - 2 * p + (i / OS);
            float oa = 1.0f, ob = 1.0f;
            if (sx >= 0 && sx < NW && sy >= 0 && sy < NH) {
                int o = sy * NW + sx;
                oa = (wa[o] != 0.0f) ? 1.0f : 0.0f;
                ob = (wb[o] != 0.0f) ? 1.0f : 0.0f;
            }
            bufOA[i] = oa; bufOB[i] = ob;
        }
        __syncthreads();
        // horizontal min: OS rows x ES cols
        for (int i = t; i < OS * ES; i += 256) {
            int y = i / ES, x = i % ES;
            float ma = 1.0f, mb = 1.0f;
            for (int d = 0; d < KW; ++d) {
                ma = fminf(ma, bufOA[y * OS + x + d]);
                mb = fminf(mb, bufOB[y * OS + x + d]);
            }
            bufHA[i] = ma; bufHB[i] = mb;
        }
        __syncthreads();
        // vertical min -> erode result (0 outside image: dilate -inf pad)
        for (int i = t; i < ES * ES; i += 256) {
            int ly = i / ES, lx = i % ES;
            int ex = x0 - p + lx, ey = y0 - p + ly;
            float ea = 0.0f, eb = 0.0f;
            if (ex >= 0 && ex < NW && ey >= 0 && ey < NH) {
                ea = 1.0f; eb = 1.0f;
                for (int d = 0; d < KW; ++d) {
                    ea = fminf(ea, bufHA[(ly + d) * ES + lx]);
                    eb = fminf(eb, bufHB[(ly + d) * ES + lx]);
                }
            }
            bufOA[i] = ea; bufOB[i] = eb;   // bufO reused for er
        }
        __syncthreads();
        // horizontal max: ES rows x 32 cols
        for (int i = t; i < ES * 32; i += 256) {
            int y = i >> 5, x = i & 31;
            float ma = 0.0f, mb = 0.0f;
            for (int d = 0; d < KW; ++d) {
                ma = fmaxf(ma, bufOA[y * ES + x + d]);
                mb = fmaxf(mb, bufOB[y * ES + x + d]);
            }
            bufHA[i] = ma; bufHB[i] = mb;   // bufH reused for hmax
        }
        __syncthreads();
        // vertical max -> dilate result for own 4 px
#pragma unroll
        for (int r = 0; r < 4; ++r) {
            int lx = t & 31, ly = (t >> 5) + r * 8;
            float ma = 0.0f, mb = 0.0f;
            for (int d = 0; d < KW; ++d) {
                ma = fmaxf(ma, bufHA[((ly + d) << 5) + lx]);
                mb = fmaxf(mb, bufHB[((ly + d) << 5) + lx]);
            }
            mA[r] = ma; mB[r] = mb;
        }
    } else {
        // brute-force fallback, never taken for k<=17; correctness insurance
#pragma unroll
        for (int r = 0; r < 4; ++r) {
            int x = x0 + (t & 31), y = y0 + (t >> 5) + r * 8;
            float ma = 0.0f, mb = 0.0f;
            for (int dy2 = -p; dy2 <= p; ++dy2) {
                int qy = y + dy2; if (qy < 0 || qy >= NH) continue;
                for (int dx2 = -p; dx2 <= p; ++dx2) {
                    int qx = x + dx2; if (qx < 0 || qx >= NW) continue;
                    if (ma >= 1.0f && mb >= 1.0f) break;
                    float ea = 1.0f, eb = 1.0f;
                    for (int dy = -p; dy <= p; ++dy) {
                        int yy = qy + dy; if (yy < 0 || yy >= NH) continue;
                        for (int dx = -p; dx <= p; ++dx) {
                            int xx = qx + dx; if (xx < 0 || xx >= NW) continue;
                            int o = yy * NW + xx;
                            if (wa[o] == 0.0f) ea = 0.0f;
                            if (wb[o] == 0.0f) eb = 0.0f;
                        }
                    }
                    ma = fmaxf(ma, ea);
                    mb = fmaxf(mb, eb);
                }
            }
            mA[r] = ma; mB[r] = mb;
        }
    }

    const float4* a0 = acc4 + (size_t)b * NHW;
    const float4* a1 = acc4 + ((size_t)NB + b) * NHW;
    float* o0 = out + (size_t)b * 4 * NHW;
    float* o1 = out + (size_t)NB * 4 * NHW + (size_t)b * 4 * NHW;

#pragma unroll
    for (int r = 0; r < 4; ++r) {
        int lx = t & 31, ly = (t >> 5) + r * 8;
        int x = x0 + lx, y = y0 + ly;
        int hw = y * NW + x;
        float4 v0 = a0[hw];
        float4 v1 = a1[hw];
        float d0 = (v0.w == 0.0f) ? 1.0f : v0.w;
        float d1 = (v1.w == 0.0f) ? 1.0f : v1.w;
        float m0 = mA[r], m1 = mB[r];
        float w00 = v0.x / d0, w01 = v0.y / d0, w02 = v0.z / d0;
        float w10 = v1.x / d1, w11 = v1.y / d1, w12 = v1.z / d1;
        o0[hw]           = m0 * w00 + (1.0f - m0) * w10;
        o0[NHW + hw]     = m0 * w01 + (1.0f - m0) * w11;
        o0[2 * NHW + hw] = m0 * w02 + (1.0f - m0) * w12;
        o0[3 * NHW + hw] = m0;
        o1[hw]           = m1 * w10 + (1.0f - m1) * w00;
        o1[NHW + hw]     = m1 * w11 + (1.0f - m1) * w01;
        o1[2 * NHW + hw] = m1 * w12 + (1.0f - m1) * w02;
        o1[3 * NHW + hw] = m1;
    }
}

extern "C" void kernel_launch(void* const* d_in, const int* in_sizes, int n_in,
                              void* d_out, int out_size, void* d_ws, size_t ws_size,
                              hipStream_t stream) {
    const float* I0  = (const float*)d_in[0];
    const float* I1  = (const float*)d_in[1];
    const float* f01 = (const float*)d_in[2];
    const float* f10 = (const float*)d_in[3];
    const int*  kptr = (const int*)d_in[4];

    float* ws = (float*)d_ws;
    const size_t n = (size_t)NB * NHW;
    // ws layout, 16n floats (proven footprint):
    //   [0, 8n)   pm0|pm1 (float4) during wmap+splat; wpl (2n floats)
    //             after splat (overlays dead pm).
    //   [8n, 16n) lab4 during lab/wmap; acc4 (2n float4) after (fully
    //             written by gather flush stores — no memset needed).
    // d_out doubles as the zeroed spill (ovf) buffer during splat; merge
    // folds it into acc4 before morph overwrites d_out.
    float4* pm0   = (float4*)ws;               // [0, 4n)
    float4* pm1   = (float4*)(ws + 4 * n);     // [4n, 8n)
    float*  wpl   = ws;                        // [0, 2n)  after splat
    float4* lab40 = (float4*)(ws + 8 * n);     // [8n, 12n)
    float4* lab41 = (float4*)(ws + 12 * n);    // [12n, 16n)
    float4* acc4  = (float4*)(ws + 8 * n);     // [8n, 16n) overlays lab4
    float4* ovf   = (float4*)d_out;            // spill scratch (zeroed)

    const int T = 256;
    int gLab = (2 * NB * NHW / 4 + T - 1) / T;
    dim3 gW(NW / 32, NH / 8, 2 * NB);
    dim3 gTile(NW / TS, NH / TS, 2 * NB);
    dim3 gCmp(NW / 32, NH / 32, NB);

    hipMemsetAsync(ovf, 0, 8 * n * sizeof(float), stream);   // zero spills
    lab_kernel<<<gLab, T, 0, stream>>>(I0, I1, lab40, lab41);
    wmap_kernel<<<gW, T, 0, stream>>>(lab40, lab41, I0, I1, f01, f10, pm0, pm1);
    splat_bin_kernel<<<gTile, 1024, 0, stream>>>(pm0, pm1, f01, f10, acc4, ovf);
    merge_kernel<<<4096, T, 0, stream>>>(acc4, ovf, wpl);
    morph_compose_kernel<<<gCmp, T, 0, stream>>>(acc4, wpl, (float*)d_out, kptr);
}

// Round 22
// 758.963 us; speedup vs baseline: 1.0352x; 1.0040x over previous
//
#include <hip/hip_runtime.h>

#define NB 4
#define NH 1024
#define NW 1024
#define NHW (NH * NW)

#define TS 32          // owned output tile side
#define HP 16          // halo
#define SRCS 64        // source region side = TS + 2*HP
#define SRC_PX (SRCS * SRCS)   // 4096
#define TILE_PX (TS * TS)      // 1024

__device__ __forceinline__ float srgb2lin(float v) {
    return v > 0.04045f ? powf((v + 0.055f) * (1.0f / 1.055f), 2.4f) : v * (1.0f / 12.92f);
}

__device__ __forceinline__ float labf(float t) {
    return t > 0.008856f ? cbrtf(t) : 7.787f * t + 4.0f / 29.0f;
}

// Lab for both images, SCALAR 1 px/thread (powf-chain latency is hidden by
// thread count — 4px/thread vectorization measured +35us). FLOAT4-padded out.
__global__ void lab_kernel(const float* __restrict__ I0, const float* __restrict__ I1,
                           float4* __restrict__ lab0, float4* __restrict__ lab1) {
    int idx = blockIdx.x * blockDim.x + threadIdx.x;
    const int total = 2 * NB * NHW;
    if (idx >= total) return;
    int img = (idx >= NB * NHW) ? 1 : 0;
    int p = idx - img * NB * NHW;
    int b = p / NHW;
    int hw = p - b * NHW;
    const float* src = (img ? I1 : I0) + (size_t)b * 3 * NHW + hw;
    float4* dst = (img ? lab1 : lab0) + ((size_t)b * NHW + hw);

    float r = srgb2lin(src[0]);
    float g = srgb2lin(src[NHW]);
    float bl = srgb2lin(src[2 * NHW]);

    float X = (0.412453f * r + 0.35758f * g + 0.180423f * bl) * (1.0f / 0.95047f);
    float Y = (0.212671f * r + 0.71516f * g + 0.072169f * bl);
    float Z = (0.019334f * r + 0.119193f * g + 0.950227f * bl) * (1.0f / 1.08883f);

    float fx = labf(X);
    float fy = labf(Y);
    float fz = labf(Z);

    *dst = make_float4(116.0f * fy - 16.0f, 500.0f * (fx - fy), 200.0f * (fy - fz), 0.0f);
}

// z-metric + exp + premultiply, both directions in one launch (z in [0,2*NB)).
// SCALAR 1 px/thread: gather-latency-bound, thread count = hiding resource.
__global__ __launch_bounds__(256) void wmap_kernel(
        const float4* __restrict__ lab0, const float4* __restrict__ lab1,
        const float* __restrict__ I0, const float* __restrict__ I1,
        const float* __restrict__ f01, const float* __restrict__ f10,
        float4* __restrict__ pm0, float4* __restrict__ pm1) {
    const int z = blockIdx.z;
    const int dir = z >> 2;            // NB == 4
    const int b = z & (NB - 1);
    const int tx = threadIdx.x & 31;
    const int ty = threadIdx.x >> 5;
    const int x = blockIdx.x * 32 + tx;
    const int y = blockIdx.y * 8 + ty;
    const int hw = y * NW + x;

    const float4* la  = (dir ? lab1 : lab0) + (size_t)b * NHW;
    const float4* lb  = (dir ? lab0 : lab1) + (size_t)b * NHW;
    const float* img = (dir ? I1 : I0) + (size_t)b * 3 * NHW;
    const float* fb  = (dir ? f10 : f01) + (size_t)b * 2 * NHW;
    float4* pm = (dir ? pm1 : pm0) + (size_t)b * NHW;

    const float fy_d = fb[hw];
    const float fx_d = fb[NHW + hw];

    float base_y = -1.0f + 2.0f * (float)y / (float)(NH - 1);
    float base_x = -1.0f + 2.0f * (float)x / (float)(NW - 1);
    float gy = 2.0f * fy_d / (float)NH + base_y;
    float gx = 2.0f * fx_d / (float)NW + base_x;
    float ys = fminf(fmaxf(((gy + 1.0f) * (float)NH - 1.0f) * 0.5f, 0.0f), (float)(NH - 1));
    float xs = fminf(fmaxf(((gx + 1.0f) * (float)NW - 1.0f) * 0.5f, 0.0f), (float)(NW - 1));
    float y0f = floorf(ys), x0f = floorf(xs);
    int y0 = (int)y0f, x0 = (int)x0f;
    int y1 = min(y0 + 1, NH - 1), x1 = min(x0 + 1, NW - 1);
    float wy = ys - y0f, wx = xs - x0f;

    const float4 p00 = lb[y0 * NW + x0];
    const float4 p01 = lb[y0 * NW + x1];
    const float4 p10 = lb[y1 * NW + x0];
    const float4 p11 = lb[y1 * NW + x1];
    const float4 pa  = la[hw];

    float vx = (p00.x * (1.0f - wx) + p01.x * wx) * (1.0f - wy)
             + (p10.x * (1.0f - wx) + p11.x * wx) * wy;
    float vy = (p00.y * (1.0f - wx) + p01.y * wx) * (1.0f - wy)
             + (p10.y * (1.0f - wx) + p11.y * wx) * wy;
    float vz = (p00.z * (1.0f - wx) + p01.z * wx) * (1.0f - wy)
             + (p10.z * (1.0f - wx) + p11.z * wx) * wy;
    float dx_ = pa.x - vx, dy_ = pa.y - vy, dz_ = pa.z - vz;
    float ss = dx_ * dx_ + dy_ * dy_ + dz_ * dz_;
    float w = expf(-0.1f * sqrtf(ss));

    pm[hw] = make_float4(img[hw] * w, img[NHW + hw] * w, img[2 * NHW + hw] * w, w);
}

// BIN + GATHER splat (measured best: 251us). Flush: ONE plain coalesced
// float4 store per own px into acc4. Spills (interior-owned, uncovered,
// pre-tested max|flow|>15): float4-cell atomics into ovf (= d_out, zeroed).
__global__ __launch_bounds__(1024, 2) void splat_bin_kernel(
        const float4* __restrict__ pm0, const float4* __restrict__ pm1,
        const float* __restrict__ f01, const float* __restrict__ f10,
        float4* __restrict__ acc4,    // [2*NB*NHW) float4, dir-major
        float4* __restrict__ ovf) {   // [2*NB*NHW) float4, dir-major (zeroed)
    __shared__ unsigned       head[33 * 33];   // sentinel 0xFFFF
    __shared__ unsigned short nxt[SRC_PX];
    __shared__ float2         flows[SRC_PX];

    const int t = threadIdx.x;
    const int z = blockIdx.z;
    const int dir = z >> 2;
    const int b = z & (NB - 1);
    const int tx0 = blockIdx.x * TS;
    const int ty0 = blockIdx.y * TS;
    const int ox = tx0 - HP;
    const int oy = ty0 - HP;

    for (int i = t; i < 33 * 33; i += 1024) head[i] = 0xFFFFu;
    __syncthreads();

    const float4* pm = (dir ? pm1 : pm0) + (size_t)b * NHW;
    const float* fb  = (dir ? f10 : f01) + (size_t)b * 2 * NHW;
    float4* a4 = acc4 + ((size_t)dir * NB + b) * NHW;
    float4* ov = ovf  + ((size_t)dir * NB + b) * NHW;

    // ---- phase 1: bin sources by floor(target) cell ----
#pragma unroll
    for (int kk = 0; kk < 4; ++kk) {
        const int i = t + kk * 1024;   // SRC_PX == 4 * 1024
        const int rx = i & (SRCS - 1);
        const int ry = i >> 6;
        const int sx = ox + rx;
        const int sy = oy + ry;
        if (sx < 0 || sx >= NW || sy < 0 || sy >= NH) continue;
        const int hw = sy * NW + sx;

        const float fy_d = fb[hw];
        const float fx_d = fb[NHW + hw];
        flows[i] = make_float2(fx_d, fy_d);

        const float px = fx_d + (float)sx;
        const float py = fy_d + (float)sy;
        const int fcx = (int)floorf(px);
        const int fcy = (int)floorf(py);
        const int mx = fcx - tx0;      // margin-relative floor cell
        const int my = fcy - ty0;

        if (mx >= -1 && mx < TS && my >= -1 && my < TS) {
            unsigned old = atomicExch(&head[(my + 1) * 33 + (mx + 1)], (unsigned)i);
            nxt[i] = (unsigned short)old;
        }

        // interior-owned, uncovered taps -> ovf. Pre-test skips provably
        // covered sources (max|flow| <= 15).
        const bool interior = (rx >= HP) && (rx < HP + TS) && (ry >= HP) && (ry < HP + TS);
        if (interior && fmaxf(fabsf(fx_d), fabsf(fy_d)) > 15.0f) {
            float4 p4; bool loaded = false;
#pragma unroll
            for (int dy = 0; dy < 2; ++dy) {
                const int yi = fcy + dy;
                if (yi < 0 || yi >= NH) continue;
                const float wgy = 1.0f - fabsf(py - (float)yi);
#pragma unroll
                for (int dx = 0; dx < 2; ++dx) {
                    const int xi = fcx + dx;
                    if (xi < 0 || xi >= NW) continue;
                    const int ttx0 = xi & ~(TS - 1);
                    const int tty0 = yi & ~(TS - 1);
                    const bool covered = (sx >= ttx0 - HP) && (sx < ttx0 + TS + HP) &&
                                         (sy >= tty0 - HP) && (sy < tty0 + TS + HP);
                    if (!covered) {
                        if (!loaded) { p4 = pm[hw]; loaded = true; }
                        const float wg = wgy * (1.0f - fabsf(px - (float)xi));
                        float* p = (float*)(ov + (yi * NW + xi));
                        atomicAdd(p + 0, p4.x * wg);
                        atomicAdd(p + 1, p4.y * wg);
                        atomicAdd(p + 2, p4.z * wg);
                        atomicAdd(p + 3, p4.w * wg);
                    }
                }
            }
        }
    }
    __syncthreads();

    // ---- phase 2: gather own cell from the 4 relevant lists ----
    {
        const int lx = t & (TS - 1);
        const int ly = t >> 5;
        const int cx = tx0 + lx;
        const int cy = ty0 + ly;
        const float cxf = (float)cx;
        const float cyf = (float)cy;

        float sx_ = 0.0f, sy_ = 0.0f, sz_ = 0.0f, sw_ = 0.0f;

#pragma unroll
        for (int dy = 0; dy < 2; ++dy) {
#pragma unroll
            for (int dx = 0; dx < 2; ++dx) {
                unsigned e = head[(ly + 1 - dy) * 33 + (lx + 1 - dx)];
                int guard = SRC_PX;
                while (e != 0xFFFFu && --guard >= 0) {
                    const float2 f = flows[e];
                    const int rx = e & (SRCS - 1);
                    const int ry = (int)e >> 6;
                    const int sxx = ox + rx;
                    const int syy = oy + ry;
                    const float px = f.x + (float)sxx;
                    const float py = f.y + (float)syy;
                    const float wg = (1.0f - fabsf(px - cxf)) * (1.0f - fabsf(py - cyf));
                    const float4 p4 = pm[syy * NW + sxx];
                    sx_ += p4.x * wg;
                    sy_ += p4.y * wg;
                    sz_ += p4.z * wg;
                    sw_ += p4.w * wg;
                    e = nxt[e];
                }
            }
        }
        a4[cy * NW + cx] = make_float4(sx_, sy_, sz_, sw_);
    }
}

// Merge overflow into acc4 and emit a PLANAR w plane for morph staging.
__global__ __launch_bounds__(256) void merge_kernel(
        float4* __restrict__ acc4, const float4* __restrict__ ovf,
        float* __restrict__ wpl) {
    const size_t total = (size_t)2 * NB * NHW;
    for (size_t i = (size_t)blockIdx.x * blockDim.x + threadIdx.x; i < total;
         i += (size_t)gridDim.x * blockDim.x) {
        float4 a = acc4[i];
        float4 o = ovf[i];
        a.x += o.x; a.y += o.y; a.z += o.z; a.w += o.w;
        acc4[i] = a;
        wpl[i] = a.w;
    }
}

// Fused morph (separable erode+dilate) + blend + store. Staging +
// denominators from planar wpl; colors from merged acc4; write-only out.
// Staged path covers p<=8 (k<=17); brute-force beyond.
__global__ __launch_bounds__(256) void morph_compose_kernel(
        const float4* __restrict__ acc4, const float* __restrict__ wpl,
        float* __restrict__ out, const int* __restrict__ kptr) {
    __shared__ float bufOA[64 * 64], bufOB[64 * 64];   // occ (OS*OS) -> er (ES*ES)
    __shared__ float bufHA[64 * 48], bufHB[64 * 48];   // hmin (OS*ES) -> hmax (ES*32)

    const int t = threadIdx.x;
    const int b = blockIdx.z;
    const int x0 = blockIdx.x * 32;
    const int y0 = blockIdx.y * 32;
    const int k = *kptr;
    const int p = k >> 1;

    const float* wa = wpl + (size_t)b * NHW;                    // dir 0
    const float* wb = wpl + ((size_t)NB + b) * NHW;             // dir 1

    float mA[4], mB[4];

    if (p <= 8) {
        const int OS = 32 + 4 * p;
        const int ES = 32 + 2 * p;
        const int KW = 2 * p + 1;
        // stage occupancy (+inf pad: OOB = 1)
        for (int i = t; i < OS * OS; i += 256) {
            int sx = x0 - 2 * p + (i % OS);
            int sy = y0 - 2 * p + (i / OS);
            float oa = 1.0f, ob = 1.0f;
            if (sx >= 0 && sx < NW && sy >= 0 && sy < NH) {
                int o = sy * NW + sx;
                oa = (wa[o] != 0.0f) ? 1.0f : 0.0f;
                ob = (wb[o] != 0.0f) ? 1.0f : 0.0f;
            }
            bufOA[i] = oa; bufOB[i] = ob;
        }
        __syncthreads();
        // horizontal min: OS rows x ES cols
        for (int i = t; i < OS * ES; i += 256) {
            int y = i / ES, x = i % ES;
            float ma = 1.0f, mb = 1.0f;
            for (int d = 0; d < KW; ++d) {
                ma = fminf(ma, bufOA[y * OS + x + d]);
                mb = fminf(mb, bufOB[y * OS + x + d]);
            }
            bufHA[i] = ma; bufHB[i] = mb;
        }
        __syncthreads();
        // vertical min -> erode result (0 outside image: dilate -inf pad)
        for (int i = t; i < ES * ES; i += 256) {
            int ly = i / ES, lx = i % ES;
            int ex = x0 - p + lx, ey = y0 - p + ly;
            float ea = 0.0f, eb = 0.0f;
            if (ex >= 0 && ex < NW && ey >= 0 && ey < NH) {
                ea = 1.0f; eb = 1.0f;
                for (int d = 0; d < KW; ++d) {
                    ea = fminf(ea, bufHA[(ly + d) * ES + lx]);
                    eb = fminf(eb, bufHB[(ly + d) * ES + lx]);
                }
            }
            bufOA[i] = ea; bufOB[i] = eb;   // bufO reused for er
        }
        __syncthreads();
        // horizontal max: ES rows x 32 cols
        for (int i = t; i < ES * 32; i += 256) {
            int y = i >> 5, x = i & 31;
            float ma = 0.0f, mb = 0.0f;
            for (int d = 0; d < KW; ++d) {
                ma = fmaxf(ma, bufOA[y * ES + x + d]);
                mb = fmaxf(mb, bufOB[y * ES + x + d]);
            }
            bufHA[i] = ma; bufHB[i] = mb;   // bufH reused for hmax
        }
        __syncthreads();
        // vertical max -> dilate result for own 4 px
#pragma unroll
        for (int r = 0; r < 4; ++r) {
            int lx = t & 31, ly = (t >> 5) + r * 8;
            float ma = 0.0f, mb = 0.0f;
            for (int d = 0; d < KW; ++d) {
                ma = fmaxf(ma, bufHA[((ly + d) << 5) + lx]);
                mb = fmaxf(mb, bufHB[((ly + d) << 5) + lx]);
            }
            mA[r] = ma; mB[r] = mb;
        }
    } else {
        // brute-force fallback, never taken for k<=17; correctness insurance
#pragma unroll
        for (int r = 0; r < 4; ++r) {
            int x = x0 + (t & 31), y = y0 + (t >> 5) + r * 8;
            float ma = 0.0f, mb = 0.0f;
            for (int dy2 = -p; dy2 <= p; ++dy2) {
                int qy = y + dy2; if (qy < 0 || qy >= NH) continue;
                for (int dx2 = -p; dx2 <= p; ++dx2) {
                    int qx = x + dx2; if (qx < 0 || qx >= NW) continue;
                    if (ma >= 1.0f && mb >= 1.0f) break;
                    float ea = 1.0f, eb = 1.0f;
                    for (int dy = -p; dy <= p; ++dy) {
                        int yy = qy + dy; if (yy < 0 || yy >= NH) continue;
                        for (int dx = -p; dx <= p; ++dx) {
                            int xx = qx + dx; if (xx < 0 || xx >= NW) continue;
                            int o = yy * NW + xx;
                            if (wa[o] == 0.0f) ea = 0.0f;
                            if (wb[o] == 0.0f) eb = 0.0f;
                        }
                    }
                    ma = fmaxf(ma, ea);
                    mb = fmaxf(mb, eb);
                }
            }
            mA[r] = ma; mB[r] = mb;
        }
    }

    const float4* a0 = acc4 + (size_t)b * NHW;
    const float4* a1 = acc4 + ((size_t)NB + b) * NHW;
    float* o0 = out + (size_t)b * 4 * NHW;
    float* o1 = out + (size_t)NB * 4 * NHW + (size_t)b * 4 * NHW;

#pragma unroll
    for (int r = 0; r < 4; ++r) {
        int lx = t & 31, ly = (t >> 5) + r * 8;
        int x = x0 + lx, y = y0 + ly;
        int hw = y * NW + x;
        float4 v0 = a0[hw];
        float4 v1 = a1[hw];
        float d0 = (v0.w == 0.0f) ? 1.0f : v0.w;
        float d1 = (v1.w == 0.0f) ? 1.0f : v1.w;
        float m0 = mA[r], m1 = mB[r];
        float w00 = v0.x / d0, w01 = v0.y / d0, w02 = v0.z / d0;
        float w10 = v1.x / d1, w11 = v1.y / d1, w12 = v1.z / d1;
        o0[hw]           = m0 * w00 + (1.0f - m0) * w10;
        o0[NHW + hw]     = m0 * w01 + (1.0f - m0) * w11;
        o0[2 * NHW + hw] = m0 * w02 + (1.0f - m0) * w12;
        o0[3 * NHW + hw] = m0;
        o1[hw]           = m1 * w10 + (1.0f - m1) * w00;
        o1[NHW + hw]     = m1 * w11 + (1.0f - m1) * w01;
        o1[2 * NHW + hw] = m1 * w12 + (1.0f - m1) * w02;
        o1[3 * NHW + hw] = m1;
    }
}

extern "C" void kernel_launch(void* const* d_in, const int* in_sizes, int n_in,
                              void* d_out, int out_size, void* d_ws, size_t ws_size,
                              hipStream_t stream) {
    const float* I0  = (const float*)d_in[0];
    const float* I1  = (const float*)d_in[1];
    const float* f01 = (const float*)d_in[2];
    const float* f10 = (const float*)d_in[3];
    const int*  kptr = (const int*)d_in[4];

    float* ws = (float*)d_ws;
    const size_t n = (size_t)NB * NHW;
    // ws layout, 16n floats (proven footprint):
    //   [0, 8n)   pm0|pm1 (float4) during wmap+splat; wpl (2n floats)
    //             after splat (overlays dead pm).
    //   [8n, 16n) lab4 during lab/wmap; acc4 (2n float4) after (fully
    //             written by gather flush stores — no memset needed).
    // d_out doubles as the zeroed spill (ovf) buffer during splat; merge
    // folds it into acc4 before morph overwrites d_out.
    float4* pm0   = (float4*)ws;               // [0, 4n)
    float4* pm1   = (float4*)(ws + 4 * n);     // [4n, 8n)
    float*  wpl   = ws;                        // [0, 2n)  after splat
    float4* lab40 = (float4*)(ws + 8 * n);     // [8n, 12n)
    float4* lab41 = (float4*)(ws + 12 * n);    // [12n, 16n)
    float4* acc4  = (float4*)(ws + 8 * n);     // [8n, 16n) overlays lab4
    float4* ovf   = (float4*)d_out;            // spill scratch (zeroed)

    const int T = 256;
    int gLab = (2 * NB * NHW + T - 1) / T;
    dim3 gW(NW / 32, NH / 8, 2 * NB);
    dim3 gTile(NW / TS, NH / TS, 2 * NB);
    dim3 gCmp(NW / 32, NH / 32, NB);

    hipMemsetAsync(ovf, 0, 8 * n * sizeof(float), stream);   // zero spills
    lab_kernel<<<gLab, T, 0, stream>>>(I0, I1, lab40, lab41);
    wmap_kernel<<<gW, T, 0, stream>>>(lab40, lab41, I0, I1, f01, f10, pm0, pm1);
    splat_bin_kernel<<<gTile, 1024, 0, stream>>>(pm0, pm1, f01, f10, acc4, ovf);
    merge_kernel<<<4096, T, 0, stream>>>(acc4, ovf, wpl);
    morph_compose_kernel<<<gCmp, T, 0, stream>>>(acc4, wpl, (float*)d_out, kptr);
}